// Round 1
// baseline (1213.371 us; speedup 1.0000x reference)
//
#include <hip/hip_runtime.h>
#include <hip/hip_bf16.h>

typedef __attribute__((ext_vector_type(8))) short short8;
typedef __attribute__((ext_vector_type(4))) float f32x4;
typedef __attribute__((ext_vector_type(8))) unsigned short u16x8;
typedef __attribute__((ext_vector_type(4))) unsigned short u16x4;

// ---------- helpers ----------
__device__ __forceinline__ unsigned short f2bf(float f) {
  unsigned u = __float_as_uint(f);
  u += 0x7fffu + ((u >> 16) & 1u);          // round-to-nearest-even
  return (unsigned short)(u >> 16);
}
__device__ __forceinline__ float silu_f(float x) { return x / (1.f + __expf(-x)); }
__device__ __forceinline__ float red16(float v) {  // sum across 16-lane group
  v += __shfl_xor(v, 1); v += __shfl_xor(v, 2);
  v += __shfl_xor(v, 4); v += __shfl_xor(v, 8);
  return v;
}
__device__ __forceinline__ void gload16(const void* g, void* l) {
  __builtin_amdgcn_global_load_lds((const __attribute__((address_space(1))) void*)g,
                                   (__attribute__((address_space(3))) void*)l, 16, 0, 0);
}

// ---------- transpose fp32 [R][C] -> bf16 [C][R] ----------
__global__ void __launch_bounds__(256) trans_kernel(const float* __restrict__ src,
                                                    unsigned short* __restrict__ dst,
                                                    int R, int C) {
  __shared__ float tile[32][33];
  const int tx = threadIdx.x & 31, ty = threadIdx.x >> 5;
  const int c = blockIdx.x * 32 + tx;
#pragma unroll
  for (int i = 0; i < 32; i += 8) {
    int r = blockIdx.y * 32 + ty + i;
    if (r < R && c < C) tile[ty + i][tx] = src[(size_t)r * C + c];
  }
  __syncthreads();
  const int rc = blockIdx.y * 32 + tx;
#pragma unroll
  for (int i = 0; i < 32; i += 8) {
    int cc = blockIdx.x * 32 + ty + i;
    if (cc < C && rc < R) dst[(size_t)cc * R + rc] = f2bf(tile[tx][ty + i]);
  }
}

// ---------- rmsnorm (D=2048) -> bf16 ----------
__global__ void __launch_bounds__(256) rmsnorm_bf16_kernel(const float* __restrict__ x,
                                                           const float* __restrict__ w,
                                                           unsigned short* __restrict__ outb) {
  const int t = blockIdx.x, tid = threadIdx.x;
  const float* xr = x + (size_t)t * 2048 + tid * 8;
  float4 v0 = *(const float4*)xr, v1 = *(const float4*)(xr + 4);
  float ss = v0.x*v0.x + v0.y*v0.y + v0.z*v0.z + v0.w*v0.w
           + v1.x*v1.x + v1.y*v1.y + v1.z*v1.z + v1.w*v1.w;
#pragma unroll
  for (int m = 1; m < 64; m <<= 1) ss += __shfl_xor(ss, m);
  __shared__ float sb[4];
  if ((tid & 63) == 0) sb[tid >> 6] = ss;
  __syncthreads();
  float rn = rsqrtf((sb[0] + sb[1] + sb[2] + sb[3]) * (1.f / 2048.f) + 1e-6f);
  const float* wr = w + tid * 8;
  float4 w0 = *(const float4*)wr, w1 = *(const float4*)(wr + 4);
  u16x8 r;
  r[0]=f2bf(v0.x*rn*w0.x); r[1]=f2bf(v0.y*rn*w0.y); r[2]=f2bf(v0.z*rn*w0.z); r[3]=f2bf(v0.w*rn*w0.w);
  r[4]=f2bf(v1.x*rn*w1.x); r[5]=f2bf(v1.y*rn*w1.y); r[6]=f2bf(v1.z*rn*w1.z); r[7]=f2bf(v1.w*rn*w1.w);
  *(u16x8*)(outb + (size_t)t * 2048 + tid * 8) = r;
}

// ---------- x1 = x + y ; h2b = bf16(rmsnorm(x1)*w) ----------
__global__ void __launch_bounds__(256) add_rmsnorm_kernel(const float* __restrict__ x,
                                                          const float* __restrict__ y,
                                                          const float* __restrict__ w,
                                                          float* __restrict__ x1,
                                                          unsigned short* __restrict__ h2b) {
  const int t = blockIdx.x, tid = threadIdx.x;
  const int c = tid * 8;
  const float* xr = x + (size_t)t * 2048 + c;
  const float* yr = y + (size_t)t * 2048 + c;
  float s[8]; float ss = 0.f;
  float4 a0 = *(const float4*)xr, a1 = *(const float4*)(xr + 4);
  float4 b0 = *(const float4*)yr, b1 = *(const float4*)(yr + 4);
  s[0]=a0.x+b0.x; s[1]=a0.y+b0.y; s[2]=a0.z+b0.z; s[3]=a0.w+b0.w;
  s[4]=a1.x+b1.x; s[5]=a1.y+b1.y; s[6]=a1.z+b1.z; s[7]=a1.w+b1.w;
#pragma unroll
  for (int j = 0; j < 8; j++) ss += s[j] * s[j];
#pragma unroll
  for (int m = 1; m < 64; m <<= 1) ss += __shfl_xor(ss, m);
  __shared__ float sb[4];
  if ((tid & 63) == 0) sb[tid >> 6] = ss;
  __syncthreads();
  float rn = rsqrtf((sb[0] + sb[1] + sb[2] + sb[3]) * (1.f / 2048.f) + 1e-6f);
  float* xo = x1 + (size_t)t * 2048 + c;
  *(float4*)xo = *(float4*)&s[0];
  *(float4*)(xo + 4) = *(float4*)&s[4];
  const float* wr = w + c;
  float4 w0 = *(const float4*)wr, w1 = *(const float4*)(wr + 4);
  float wv[8] = {w0.x,w0.y,w0.z,w0.w,w1.x,w1.y,w1.z,w1.w};
  u16x8 r;
#pragma unroll
  for (int j = 0; j < 8; j++) r[j] = f2bf(s[j] * rn * wv[j]);
  *(u16x8*)(h2b + (size_t)t * 2048 + c) = r;
}

// ---------- bf16 GEMM: C[M,N] = A[M,K] * Bt[N,K]^T  (m97-style) ----------
__global__ void __launch_bounds__(256) gemm_bt_kernel(const unsigned short* __restrict__ A,
                                                      const unsigned short* __restrict__ Bt,
                                                      float* __restrict__ C,
                                                      int M, int N, int K) {
  __shared__ unsigned short As[128][32];
  __shared__ unsigned short Bs[128][32];
  const int tid = threadIdx.x;
  const int m0 = blockIdx.x << 7, n0 = blockIdx.y << 7;
  const int wave = tid >> 6, lane = tid & 63;
  const int wm = (wave >> 1) << 6, wn = (wave & 1) << 6;
  const int lrow = lane >> 2, lcol = lane & 3;       // staging: 4 lanes/row, 16B each
  const int ar0 = wave * 16 + lrow;                  // rows 0..63
  const int ar1 = ar0 + 64;                          // rows 64..127
  int br0 = n0 + ar0; br0 = br0 < N ? br0 : N - 1;   // clamp for partial N tiles
  int br1 = n0 + ar1; br1 = br1 < N ? br1 : N - 1;
  // XOR-swizzle the k-unit on the GLOBAL side (linear LDS dest, rule #21)
  const unsigned short* Aptr0 = A + (size_t)(m0 + ar0) * K + ((lcol ^ (ar0 & 3)) << 3);
  const unsigned short* Aptr1 = A + (size_t)(m0 + ar1) * K + ((lcol ^ (ar1 & 3)) << 3);
  const unsigned short* Bptr0 = Bt + (size_t)br0 * K + ((lcol ^ (ar0 & 3)) << 3);
  const unsigned short* Bptr1 = Bt + (size_t)br1 * K + ((lcol ^ (ar1 & 3)) << 3);
  unsigned short* lA0 = &As[wave * 16][0];
  unsigned short* lA1 = &As[64 + wave * 16][0];
  unsigned short* lB0 = &Bs[wave * 16][0];
  unsigned short* lB1 = &Bs[64 + wave * 16][0];
  const int frow = lane & 15, fkb = lane >> 4;
  f32x4 acc[4][4];
#pragma unroll
  for (int i = 0; i < 4; i++)
#pragma unroll
    for (int j = 0; j < 4; j++) acc[i][j] = (f32x4){0.f, 0.f, 0.f, 0.f};

  for (int k0 = 0; k0 < K; k0 += 32) {
    gload16(Aptr0 + k0, lA0);
    gload16(Aptr1 + k0, lA1);
    gload16(Bptr0 + k0, lB0);
    gload16(Bptr1 + k0, lB1);
    __syncthreads();
    short8 af[4], bfr[4];
#pragma unroll
    for (int i = 0; i < 4; i++) {
      int ra = wm + i * 16 + frow;
      af[i] = *(const short8*)&As[ra][(fkb ^ (ra & 3)) << 3];
      int rb = wn + i * 16 + frow;
      bfr[i] = *(const short8*)&Bs[rb][(fkb ^ (rb & 3)) << 3];
    }
#pragma unroll
    for (int i = 0; i < 4; i++)
#pragma unroll
      for (int j = 0; j < 4; j++)
        acc[i][j] = __builtin_amdgcn_mfma_f32_16x16x32_bf16(af[i], bfr[j], acc[i][j], 0, 0, 0);
    __syncthreads();
  }
  const int crow = (lane >> 4) << 2, ccol = lane & 15;
#pragma unroll
  for (int i = 0; i < 4; i++) {
    const int gr = m0 + wm + i * 16 + crow;
#pragma unroll
    for (int j = 0; j < 4; j++) {
      const int gc = n0 + wn + j * 16 + ccol;
      if (gc < N) {
#pragma unroll
        for (int r = 0; r < 4; r++) C[(size_t)(gr + r) * N + gc] = acc[i][j][r];
      }
    }
  }
}

// ---------- causal dwconv(K=4) + silu + per-head l2norm ----------
__global__ void __launch_bounds__(256) conv_kernel(const float* __restrict__ proj,
                                                   const float* __restrict__ cq,
                                                   const float* __restrict__ ck,
                                                   const float* __restrict__ cv,
                                                   float* __restrict__ q, float* __restrict__ k,
                                                   float* __restrict__ v) {
  const int t = blockIdx.x, tid = threadIdx.x;
  const int c = tid << 3;
  float aq[8] = {0,0,0,0,0,0,0,0}, ak[8] = {0,0,0,0,0,0,0,0}, av[8] = {0,0,0,0,0,0,0,0};
#pragma unroll
  for (int i = 0; i < 4; i++) {
    const int tt = t + i - 3;
    if (tt < 0) continue;
    const float* pr = proj + (size_t)tt * 6144;
    float pq[8], pk[8], pv[8], w0[8], w1[8], w2[8];
    *(float4*)&pq[0] = *(const float4*)(pr + c);        *(float4*)&pq[4] = *(const float4*)(pr + c + 4);
    *(float4*)&pk[0] = *(const float4*)(pr + 2048 + c); *(float4*)&pk[4] = *(const float4*)(pr + 2048 + c + 4);
    *(float4*)&pv[0] = *(const float4*)(pr + 4096 + c); *(float4*)&pv[4] = *(const float4*)(pr + 4096 + c + 4);
    *(float4*)&w0[0] = *(const float4*)(cq + i * 2048 + c); *(float4*)&w0[4] = *(const float4*)(cq + i * 2048 + c + 4);
    *(float4*)&w1[0] = *(const float4*)(ck + i * 2048 + c); *(float4*)&w1[4] = *(const float4*)(ck + i * 2048 + c + 4);
    *(float4*)&w2[0] = *(const float4*)(cv + i * 2048 + c); *(float4*)&w2[4] = *(const float4*)(cv + i * 2048 + c + 4);
#pragma unroll
    for (int j = 0; j < 8; j++) { aq[j] += w0[j]*pq[j]; ak[j] += w1[j]*pk[j]; av[j] += w2[j]*pv[j]; }
  }
  float sq[8], sk[8], sv[8]; float ssq = 0.f, ssk = 0.f;
#pragma unroll
  for (int j = 0; j < 8; j++) {
    sq[j] = silu_f(aq[j]); ssq += sq[j]*sq[j];
    sk[j] = silu_f(ak[j]); ssk += sk[j]*sk[j];
    sv[j] = silu_f(av[j]);
  }
  ssq = red16(ssq); ssk = red16(ssk);   // 16 lanes cover one head (128 ch)
  const float rq = rsqrtf(ssq + 1e-6f) * 0.08838834764831845f;  // * DK^-0.5
  const float rk = rsqrtf(ssk + 1e-6f);
  float oq[8], ok[8];
#pragma unroll
  for (int j = 0; j < 8; j++) { oq[j] = sq[j]*rq; ok[j] = sk[j]*rk; }
  float* qo = q + (size_t)t * 2048 + c;
  *(float4*)qo = *(float4*)&oq[0]; *(float4*)(qo + 4) = *(float4*)&oq[4];
  float* ko = k + (size_t)t * 2048 + c;
  *(float4*)ko = *(float4*)&ok[0]; *(float4*)(ko + 4) = *(float4*)&ok[4];
  float* vo = v + (size_t)t * 2048 + c;
  *(float4*)vo = *(float4*)&sv[0]; *(float4*)(vo + 4) = *(float4*)&sv[4];
}

// ---------- g, beta, ga->bf16 ----------
__global__ void __launch_bounds__(64) gates_kernel(const float* __restrict__ small,
                                                   const float* __restrict__ wfb,
                                                   const float* __restrict__ a_log,
                                                   const float* __restrict__ dtb,
                                                   float* __restrict__ g, float* __restrict__ beta,
                                                   unsigned short* __restrict__ gab) {
  const int t = blockIdx.x, tid = threadIdx.x;
  const float* srow = small + (size_t)t * 272;
  if (tid < 16) {
    float d = dtb[tid];
    for (int j = 0; j < 128; j++) d += srow[j] * wfb[j * 16 + tid];
    float sp = (d > 20.f) ? d : log1pf(expf(d));
    g[t * 16 + tid] = -expf(a_log[tid]) * sp;
    float b = srow[128 + tid];
    beta[t * 16 + tid] = 1.f / (1.f + expf(-b));
  }
  for (int j = tid; j < 128; j += 64) gab[(size_t)t * 128 + j] = f2bf(srow[144 + j]);
}

// ---------- gated delta-rule scan: one wave = 4 v-columns of one head ----------
__global__ void __launch_bounds__(64) scan_kernel(const float* __restrict__ q,
                                                  const float* __restrict__ k,
                                                  const float* __restrict__ v,
                                                  const float* __restrict__ g,
                                                  const float* __restrict__ beta,
                                                  float* __restrict__ o) {
  const int b = blockIdx.x;            // 512 = 16 heads * 32 slices
  const int h = b >> 5;
  const int vbase = (b & 31) << 2;
  const int lane = threadIdx.x;
  const int kl = lane & 15, vl = lane >> 4;
  const int vcol = vbase + vl;
  const int koff = h * 128 + kl * 8;
  const int voff = h * 128 + vcol;
  float S[8] = {0,0,0,0,0,0,0,0};
  for (int t = 0; t < 1024; t++) {
    const float gt = g[t * 16 + h];
    const float bt = beta[t * 16 + h];
    const float eg = __expf(gt);
    const float* kp = k + (size_t)t * 2048 + koff;
    const float* qp = q + (size_t)t * 2048 + koff;
    float4 k0 = *(const float4*)kp, k1 = *(const float4*)(kp + 4);
    float4 q0 = *(const float4*)qp, q1 = *(const float4*)(qp + 4);
    const float vv = v[(size_t)t * 2048 + voff];
    float kk[8] = {k0.x,k0.y,k0.z,k0.w,k1.x,k1.y,k1.z,k1.w};
    float qq[8] = {q0.x,q0.y,q0.z,q0.w,q1.x,q1.y,q1.z,q1.w};
    float kS = 0.f, qS = 0.f, qk = 0.f;
#pragma unroll
    for (int i = 0; i < 8; i++) { kS += kk[i]*S[i]; qS += qq[i]*S[i]; qk += qq[i]*kk[i]; }
    kS = red16(kS); qS = red16(qS); qk = red16(qk);
    const float delta = bt * (vv - eg * kS);
#pragma unroll
    for (int i = 0; i < 8; i++) S[i] = eg * S[i] + kk[i] * delta;
    if (kl == 0) o[(size_t)t * 2048 + voff] = eg * qS + qk * delta;
  }
}

// ---------- o_gated = bf16(rmsnorm_head(o)*w * silu(gate)) ----------
__global__ void __launch_bounds__(256) gate_o_kernel(const float* __restrict__ o,
                                                     const float* __restrict__ gate,
                                                     const float* __restrict__ onw,
                                                     unsigned short* __restrict__ ogb) {
  const int t = blockIdx.x, tid = threadIdx.x;
  const int c = tid << 3;
  const float* orow = o + (size_t)t * 2048 + c;
  float ov[8]; *(float4*)&ov[0] = *(const float4*)orow; *(float4*)&ov[4] = *(const float4*)(orow + 4);
  float ss = 0.f;
#pragma unroll
  for (int j = 0; j < 8; j++) ss += ov[j] * ov[j];
  ss = red16(ss);
  const float rn = rsqrtf(ss * (1.f / 128.f) + 1e-6f);
  const int dv = (tid & 15) << 3;
  float wv[8]; *(float4*)&wv[0] = *(const float4*)(onw + dv); *(float4*)&wv[4] = *(const float4*)(onw + dv + 4);
  const float* grow = gate + (size_t)t * 2048 + c;
  float gv[8]; *(float4*)&gv[0] = *(const float4*)grow; *(float4*)&gv[4] = *(const float4*)(grow + 4);
  u16x8 r;
#pragma unroll
  for (int j = 0; j < 8; j++) r[j] = f2bf(ov[j] * rn * wv[j] * silu_f(gv[j]));
  *(u16x8*)(ogb + (size_t)t * 2048 + c) = r;
}

// ---------- swiglu: mid = bf16(silu(m1[:, :8192]) * m1[:, 8192:]) ----------
__global__ void swiglu_kernel(const float* __restrict__ m1, unsigned short* __restrict__ mid) {
  const int NU = 1024 * 2048;  // units of 4 along I
  for (int u = blockIdx.x * blockDim.x + threadIdx.x; u < NU; u += gridDim.x * blockDim.x) {
    const int t = u >> 11;
    const int j4 = (u & 2047) << 2;
    const float* base = m1 + (size_t)t * 16384;
    float4 gv = *(const float4*)(base + j4);
    float4 uv = *(const float4*)(base + 8192 + j4);
    u16x4 r;
    r[0] = f2bf(silu_f(gv.x) * uv.x);
    r[1] = f2bf(silu_f(gv.y) * uv.y);
    r[2] = f2bf(silu_f(gv.z) * uv.z);
    r[3] = f2bf(silu_f(gv.w) * uv.w);
    *(u16x4*)(mid + (size_t)t * 8192 + j4) = r;
  }
}

// ---------- out = a + b ----------
__global__ void final_add_kernel(const float* __restrict__ a, const float* __restrict__ b,
                                 float* __restrict__ out) {
  const int NU = 1024 * 512;
  for (int u = blockIdx.x * blockDim.x + threadIdx.x; u < NU; u += gridDim.x * blockDim.x) {
    float4 va = ((const float4*)a)[u];
    float4 vb = ((const float4*)b)[u];
    va.x += vb.x; va.y += vb.y; va.z += vb.z; va.w += vb.w;
    ((float4*)out)[u] = va;
  }
}

// ---------- ws layout (bytes) ----------
constexpr size_t SZ_WQKVT   = (size_t)6144 * 2048 * 2;
constexpr size_t SZ_WSMALLT = (size_t)272 * 2048 * 2;
constexpr size_t SZ_WGBT    = (size_t)2048 * 128 * 2;
constexpr size_t SZ_WOT     = (size_t)2048 * 2048 * 2;
constexpr size_t SZ_WMLP1T  = (size_t)16384 * 2048 * 2;
constexpr size_t SZ_WDOWNT  = (size_t)2048 * 8192 * 2;
constexpr size_t OFF_WQKVT   = 0;
constexpr size_t OFF_WSMALLT = OFF_WQKVT + SZ_WQKVT;
constexpr size_t OFF_WGBT    = OFF_WSMALLT + SZ_WSMALLT;
constexpr size_t OFF_WOT     = OFF_WGBT + SZ_WGBT;
constexpr size_t OFF_WMLP1T  = OFF_WOT + SZ_WOT;
constexpr size_t OFF_WDOWNT  = OFF_WMLP1T + SZ_WMLP1T;
constexpr size_t A0          = OFF_WDOWNT + SZ_WDOWNT;          // 135,856,128
constexpr size_t OFF_HB    = A0;
constexpr size_t OFF_PROJ  = OFF_HB + (size_t)1024 * 2048 * 2;
constexpr size_t OFF_SMALL = OFF_PROJ + (size_t)1024 * 6144 * 4;
constexpr size_t OFF_Q     = OFF_SMALL + (size_t)1024 * 272 * 4;
constexpr size_t OFF_K     = OFF_Q + (size_t)1024 * 2048 * 4;
constexpr size_t OFF_V     = OFF_K + (size_t)1024 * 2048 * 4;
constexpr size_t OFF_G     = OFF_V + (size_t)1024 * 2048 * 4;
constexpr size_t OFF_BETA  = OFF_G + (size_t)1024 * 16 * 4;
constexpr size_t OFF_GAB   = OFF_BETA + (size_t)1024 * 16 * 4;
constexpr size_t OFF_GATE  = OFF_GAB + (size_t)1024 * 128 * 2;
constexpr size_t OFF_O     = OFF_GATE + (size_t)1024 * 2048 * 4;
constexpr size_t OFF_OGB   = OFF_O + (size_t)1024 * 2048 * 4;
constexpr size_t OFF_OPROJ = OFF_OGB + (size_t)1024 * 2048 * 2;
constexpr size_t OFF_X1    = OFF_OPROJ + (size_t)1024 * 2048 * 4;
constexpr size_t OFF_H2B   = OFF_X1 + (size_t)1024 * 2048 * 4;
// liveness aliases: everything from HB..O is dead before MLP1 is written, etc.
constexpr size_t OFF_MLP1   = A0;                                 // 64 MB
constexpr size_t OFF_MID    = A0 + (size_t)1024 * 16384 * 4;      // overlaps dead O/OGB/OPROJ
constexpr size_t OFF_MLPOUT = OFF_H2B + (size_t)1024 * 2048 * 2;
constexpr size_t WS_NEED    = OFF_MLPOUT + (size_t)1024 * 2048 * 4;  // ~242 MB

extern "C" void kernel_launch(void* const* d_in, const int* in_sizes, int n_in,
                              void* d_out, int out_size, void* d_ws, size_t ws_size,
                              hipStream_t stream) {
  (void)in_sizes; (void)n_in; (void)out_size;
  const float* x     = (const float*)d_in[0];
  const float* wq    = (const float*)d_in[1];
  const float* wk    = (const float*)d_in[2];
  const float* wv    = (const float*)d_in[3];
  const float* cq    = (const float*)d_in[4];
  const float* ck    = (const float*)d_in[5];
  const float* cv    = (const float*)d_in[6];
  const float* wfa   = (const float*)d_in[7];
  const float* wfb   = (const float*)d_in[8];
  const float* wb    = (const float*)d_in[9];
  const float* wga   = (const float*)d_in[10];
  const float* wgb   = (const float*)d_in[11];
  const float* a_log = (const float*)d_in[12];
  const float* dtb   = (const float*)d_in[13];
  const float* onw   = (const float*)d_in[14];
  const float* wo    = (const float*)d_in[15];
  const float* ln1   = (const float*)d_in[16];
  const float* ln2   = (const float*)d_in[17];
  const float* wgate = (const float*)d_in[18];
  const float* wup   = (const float*)d_in[19];
  const float* wdown = (const float*)d_in[20];
  float* out = (float*)d_out;
  char* ws = (char*)d_ws;
  if (ws_size < WS_NEED) return;  // leaves d_out poisoned -> visible failure

  unsigned short* wqkvT   = (unsigned short*)(ws + OFF_WQKVT);
  unsigned short* wsmallT = (unsigned short*)(ws + OFF_WSMALLT);
  unsigned short* wgbT    = (unsigned short*)(ws + OFF_WGBT);
  unsigned short* woT     = (unsigned short*)(ws + OFF_WOT);
  unsigned short* wmlp1T  = (unsigned short*)(ws + OFF_WMLP1T);
  unsigned short* wdownT  = (unsigned short*)(ws + OFF_WDOWNT);
  unsigned short* hb      = (unsigned short*)(ws + OFF_HB);
  float* projf  = (float*)(ws + OFF_PROJ);
  float* smallf = (float*)(ws + OFF_SMALL);
  float* qf     = (float*)(ws + OFF_Q);
  float* kf     = (float*)(ws + OFF_K);
  float* vf     = (float*)(ws + OFF_V);
  float* gf     = (float*)(ws + OFF_G);
  float* betaf  = (float*)(ws + OFF_BETA);
  unsigned short* gab = (unsigned short*)(ws + OFF_GAB);
  float* gatef  = (float*)(ws + OFF_GATE);
  float* of     = (float*)(ws + OFF_O);
  unsigned short* ogb = (unsigned short*)(ws + OFF_OGB);
  float* oprojf = (float*)(ws + OFF_OPROJ);
  float* x1f    = (float*)(ws + OFF_X1);
  unsigned short* h2b = (unsigned short*)(ws + OFF_H2B);
  float* mlp1f  = (float*)(ws + OFF_MLP1);
  unsigned short* midb = (unsigned short*)(ws + OFF_MID);
  float* mlpoutf = (float*)(ws + OFF_MLPOUT);

  // weight transposes (fp32 -> bf16, [R][C] -> [C][R])
  trans_kernel<<<dim3(64, 64), 256, 0, stream>>>(wq, wqkvT, 2048, 2048);
  trans_kernel<<<dim3(64, 64), 256, 0, stream>>>(wk, wqkvT + (size_t)2048 * 2048, 2048, 2048);
  trans_kernel<<<dim3(64, 64), 256, 0, stream>>>(wv, wqkvT + (size_t)4096 * 2048, 2048, 2048);
  trans_kernel<<<dim3(4, 64), 256, 0, stream>>>(wfa, wsmallT, 2048, 128);
  trans_kernel<<<dim3(1, 64), 256, 0, stream>>>(wb, wsmallT + (size_t)128 * 2048, 2048, 16);
  trans_kernel<<<dim3(4, 64), 256, 0, stream>>>(wga, wsmallT + (size_t)144 * 2048, 2048, 128);
  trans_kernel<<<dim3(64, 4), 256, 0, stream>>>(wgb, wgbT, 128, 2048);
  trans_kernel<<<dim3(64, 64), 256, 0, stream>>>(wo, woT, 2048, 2048);
  trans_kernel<<<dim3(256, 64), 256, 0, stream>>>(wgate, wmlp1T, 2048, 8192);
  trans_kernel<<<dim3(256, 64), 256, 0, stream>>>(wup, wmlp1T + (size_t)8192 * 2048, 2048, 8192);
  trans_kernel<<<dim3(64, 256), 256, 0, stream>>>(wdown, wdownT, 8192, 2048);

  rmsnorm_bf16_kernel<<<1024, 256, 0, stream>>>(x, ln1, hb);
  gemm_bt_kernel<<<dim3(8, 48), 256, 0, stream>>>(hb, wqkvT, projf, 1024, 6144, 2048);
  gemm_bt_kernel<<<dim3(8, 3), 256, 0, stream>>>(hb, wsmallT, smallf, 1024, 272, 2048);
  conv_kernel<<<1024, 256, 0, stream>>>(projf, cq, ck, cv, qf, kf, vf);
  gates_kernel<<<1024, 64, 0, stream>>>(smallf, wfb, a_log, dtb, gf, betaf, gab);
  gemm_bt_kernel<<<dim3(8, 16), 256, 0, stream>>>(gab, wgbT, gatef, 1024, 2048, 128);
  scan_kernel<<<512, 64, 0, stream>>>(qf, kf, vf, gf, betaf, of);
  gate_o_kernel<<<1024, 256, 0, stream>>>(of, gatef, onw, ogb);
  gemm_bt_kernel<<<dim3(8, 16), 256, 0, stream>>>(ogb, woT, oprojf, 1024, 2048, 2048);
  add_rmsnorm_kernel<<<1024, 256, 0, stream>>>(x, oprojf, ln2, x1f, h2b);
  gemm_bt_kernel<<<dim3(8, 128), 256, 0, stream>>>(h2b, wmlp1T, mlp1f, 1024, 16384, 2048);
  swiglu_kernel<<<2048, 256, 0, stream>>>(mlp1f, midb);
  gemm_bt_kernel<<<dim3(8, 16), 256, 0, stream>>>(midb, wdownT, mlpoutf, 1024, 2048, 8192);
  final_add_kernel<<<2048, 256, 0, stream>>>(x1f, mlpoutf, out);
}

// Round 2
// 1015.338 us; speedup vs baseline: 1.1950x; 1.1950x over previous
//
#include <hip/hip_runtime.h>
#include <hip/hip_bf16.h>

typedef __attribute__((ext_vector_type(8))) short short8;
typedef __attribute__((ext_vector_type(4))) float f32x4;
typedef __attribute__((ext_vector_type(8))) unsigned short u16x8;
typedef __attribute__((ext_vector_type(4))) unsigned short u16x4;

// ---------- helpers ----------
__device__ __forceinline__ unsigned short f2bf(float f) {
  unsigned u = __float_as_uint(f);
  u += 0x7fffu + ((u >> 16) & 1u);          // round-to-nearest-even
  return (unsigned short)(u >> 16);
}
__device__ __forceinline__ float silu_f(float x) { return x / (1.f + __expf(-x)); }
__device__ __forceinline__ float red16(float v) {  // sum across 16-lane group (shfl version)
  v += __shfl_xor(v, 1); v += __shfl_xor(v, 2);
  v += __shfl_xor(v, 4); v += __shfl_xor(v, 8);
  return v;
}
// DPP 16-lane sum: quad xor1, quad xor2, half-mirror (quads 0<->1,2<->3), mirror (0<->3,1<->2)
template <int CTRL>
__device__ __forceinline__ float dpp_mv(float v) {
  return __int_as_float(__builtin_amdgcn_update_dpp(0, __float_as_int(v), CTRL, 0xF, 0xF, true));
}
__device__ __forceinline__ float red16d(float v) {
  v += dpp_mv<0xB1>(v);   // quad_perm [1,0,3,2]
  v += dpp_mv<0x4E>(v);   // quad_perm [2,3,0,1]
  v += dpp_mv<0x141>(v);  // row_half_mirror
  v += dpp_mv<0x140>(v);  // row_mirror
  return v;
}
__device__ __forceinline__ void gload16(const void* g, void* l) {
  __builtin_amdgcn_global_load_lds((const __attribute__((address_space(1))) void*)g,
                                   (__attribute__((address_space(3))) void*)l, 16, 0, 0);
}

// ---------- transpose fp32 [R][C] -> bf16 [C][R] ----------
__global__ void __launch_bounds__(256) trans_kernel(const float* __restrict__ src,
                                                    unsigned short* __restrict__ dst,
                                                    int R, int C) {
  __shared__ float tile[32][33];
  const int tx = threadIdx.x & 31, ty = threadIdx.x >> 5;
  const int c = blockIdx.x * 32 + tx;
#pragma unroll
  for (int i = 0; i < 32; i += 8) {
    int r = blockIdx.y * 32 + ty + i;
    if (r < R && c < C) tile[ty + i][tx] = src[(size_t)r * C + c];
  }
  __syncthreads();
  const int rc = blockIdx.y * 32 + tx;
#pragma unroll
  for (int i = 0; i < 32; i += 8) {
    int cc = blockIdx.x * 32 + ty + i;
    if (cc < C && rc < R) dst[(size_t)cc * R + rc] = f2bf(tile[tx][ty + i]);
  }
}

// ---------- rmsnorm (D=2048) -> bf16 ----------
__global__ void __launch_bounds__(256) rmsnorm_bf16_kernel(const float* __restrict__ x,
                                                           const float* __restrict__ w,
                                                           unsigned short* __restrict__ outb) {
  const int t = blockIdx.x, tid = threadIdx.x;
  const float* xr = x + (size_t)t * 2048 + tid * 8;
  float4 v0 = *(const float4*)xr, v1 = *(const float4*)(xr + 4);
  float ss = v0.x*v0.x + v0.y*v0.y + v0.z*v0.z + v0.w*v0.w
           + v1.x*v1.x + v1.y*v1.y + v1.z*v1.z + v1.w*v1.w;
#pragma unroll
  for (int m = 1; m < 64; m <<= 1) ss += __shfl_xor(ss, m);
  __shared__ float sb[4];
  if ((tid & 63) == 0) sb[tid >> 6] = ss;
  __syncthreads();
  float rn = rsqrtf((sb[0] + sb[1] + sb[2] + sb[3]) * (1.f / 2048.f) + 1e-6f);
  const float* wr = w + tid * 8;
  float4 w0 = *(const float4*)wr, w1 = *(const float4*)(wr + 4);
  u16x8 r;
  r[0]=f2bf(v0.x*rn*w0.x); r[1]=f2bf(v0.y*rn*w0.y); r[2]=f2bf(v0.z*rn*w0.z); r[3]=f2bf(v0.w*rn*w0.w);
  r[4]=f2bf(v1.x*rn*w1.x); r[5]=f2bf(v1.y*rn*w1.y); r[6]=f2bf(v1.z*rn*w1.z); r[7]=f2bf(v1.w*rn*w1.w);
  *(u16x8*)(outb + (size_t)t * 2048 + tid * 8) = r;
}

// ---------- x1 = x + y ; h2b = bf16(rmsnorm(x1)*w) ----------
__global__ void __launch_bounds__(256) add_rmsnorm_kernel(const float* __restrict__ x,
                                                          const float* __restrict__ y,
                                                          const float* __restrict__ w,
                                                          float* __restrict__ x1,
                                                          unsigned short* __restrict__ h2b) {
  const int t = blockIdx.x, tid = threadIdx.x;
  const int c = tid * 8;
  const float* xr = x + (size_t)t * 2048 + c;
  const float* yr = y + (size_t)t * 2048 + c;
  float s[8]; float ss = 0.f;
  float4 a0 = *(const float4*)xr, a1 = *(const float4*)(xr + 4);
  float4 b0 = *(const float4*)yr, b1 = *(const float4*)(yr + 4);
  s[0]=a0.x+b0.x; s[1]=a0.y+b0.y; s[2]=a0.z+b0.z; s[3]=a0.w+b0.w;
  s[4]=a1.x+b1.x; s[5]=a1.y+b1.y; s[6]=a1.z+b1.z; s[7]=a1.w+b1.w;
#pragma unroll
  for (int j = 0; j < 8; j++) ss += s[j] * s[j];
#pragma unroll
  for (int m = 1; m < 64; m <<= 1) ss += __shfl_xor(ss, m);
  __shared__ float sb[4];
  if ((tid & 63) == 0) sb[tid >> 6] = ss;
  __syncthreads();
  float rn = rsqrtf((sb[0] + sb[1] + sb[2] + sb[3]) * (1.f / 2048.f) + 1e-6f);
  float* xo = x1 + (size_t)t * 2048 + c;
  *(float4*)xo = *(float4*)&s[0];
  *(float4*)(xo + 4) = *(float4*)&s[4];
  const float* wr = w + c;
  float4 w0 = *(const float4*)wr, w1 = *(const float4*)(wr + 4);
  float wv[8] = {w0.x,w0.y,w0.z,w0.w,w1.x,w1.y,w1.z,w1.w};
  u16x8 r;
#pragma unroll
  for (int j = 0; j < 8; j++) r[j] = f2bf(s[j] * rn * wv[j]);
  *(u16x8*)(h2b + (size_t)t * 2048 + c) = r;
}

// ---------- bf16 GEMM: C[M,N] = A[M,K] * Bt[N,K]^T  (m97-style) ----------
__global__ void __launch_bounds__(256) gemm_bt_kernel(const unsigned short* __restrict__ A,
                                                      const unsigned short* __restrict__ Bt,
                                                      float* __restrict__ C,
                                                      int M, int N, int K) {
  __shared__ unsigned short As[128][32];
  __shared__ unsigned short Bs[128][32];
  const int tid = threadIdx.x;
  const int m0 = blockIdx.x << 7, n0 = blockIdx.y << 7;
  const int wave = tid >> 6, lane = tid & 63;
  const int wm = (wave >> 1) << 6, wn = (wave & 1) << 6;
  const int lrow = lane >> 2, lcol = lane & 3;
  const int ar0 = wave * 16 + lrow;
  const int ar1 = ar0 + 64;
  int br0 = n0 + ar0; br0 = br0 < N ? br0 : N - 1;
  int br1 = n0 + ar1; br1 = br1 < N ? br1 : N - 1;
  const unsigned short* Aptr0 = A + (size_t)(m0 + ar0) * K + ((lcol ^ (ar0 & 3)) << 3);
  const unsigned short* Aptr1 = A + (size_t)(m0 + ar1) * K + ((lcol ^ (ar1 & 3)) << 3);
  const unsigned short* Bptr0 = Bt + (size_t)br0 * K + ((lcol ^ (ar0 & 3)) << 3);
  const unsigned short* Bptr1 = Bt + (size_t)br1 * K + ((lcol ^ (ar1 & 3)) << 3);
  unsigned short* lA0 = &As[wave * 16][0];
  unsigned short* lA1 = &As[64 + wave * 16][0];
  unsigned short* lB0 = &Bs[wave * 16][0];
  unsigned short* lB1 = &Bs[64 + wave * 16][0];
  const int frow = lane & 15, fkb = lane >> 4;
  f32x4 acc[4][4];
#pragma unroll
  for (int i = 0; i < 4; i++)
#pragma unroll
    for (int j = 0; j < 4; j++) acc[i][j] = (f32x4){0.f, 0.f, 0.f, 0.f};

  for (int k0 = 0; k0 < K; k0 += 32) {
    gload16(Aptr0 + k0, lA0);
    gload16(Aptr1 + k0, lA1);
    gload16(Bptr0 + k0, lB0);
    gload16(Bptr1 + k0, lB1);
    __syncthreads();
    short8 af[4], bfr[4];
#pragma unroll
    for (int i = 0; i < 4; i++) {
      int ra = wm + i * 16 + frow;
      af[i] = *(const short8*)&As[ra][(fkb ^ (ra & 3)) << 3];
      int rb = wn + i * 16 + frow;
      bfr[i] = *(const short8*)&Bs[rb][(fkb ^ (rb & 3)) << 3];
    }
#pragma unroll
    for (int i = 0; i < 4; i++)
#pragma unroll
      for (int j = 0; j < 4; j++)
        acc[i][j] = __builtin_amdgcn_mfma_f32_16x16x32_bf16(af[i], bfr[j], acc[i][j], 0, 0, 0);
    __syncthreads();
  }
  const int crow = (lane >> 4) << 2, ccol = lane & 15;
#pragma unroll
  for (int i = 0; i < 4; i++) {
    const int gr = m0 + wm + i * 16 + crow;
#pragma unroll
    for (int j = 0; j < 4; j++) {
      const int gc = n0 + wn + j * 16 + ccol;
      if (gc < N) {
#pragma unroll
        for (int r = 0; r < 4; r++) C[(size_t)(gr + r) * N + gc] = acc[i][j][r];
      }
    }
  }
}

// ---------- causal dwconv(K=4) + silu + per-head l2norm + qk dot ----------
__global__ void __launch_bounds__(256) conv_kernel(const float* __restrict__ proj,
                                                   const float* __restrict__ cq,
                                                   const float* __restrict__ ck,
                                                   const float* __restrict__ cv,
                                                   float* __restrict__ q, float* __restrict__ k,
                                                   float* __restrict__ v,
                                                   float* __restrict__ qkbuf) {
  const int t = blockIdx.x, tid = threadIdx.x;
  const int c = tid << 3;
  float aq[8] = {0,0,0,0,0,0,0,0}, ak[8] = {0,0,0,0,0,0,0,0}, av[8] = {0,0,0,0,0,0,0,0};
#pragma unroll
  for (int i = 0; i < 4; i++) {
    const int tt = t + i - 3;
    if (tt < 0) continue;
    const float* pr = proj + (size_t)tt * 6144;
    float pq[8], pk[8], pv[8], w0[8], w1[8], w2[8];
    *(float4*)&pq[0] = *(const float4*)(pr + c);        *(float4*)&pq[4] = *(const float4*)(pr + c + 4);
    *(float4*)&pk[0] = *(const float4*)(pr + 2048 + c); *(float4*)&pk[4] = *(const float4*)(pr + 2048 + c + 4);
    *(float4*)&pv[0] = *(const float4*)(pr + 4096 + c); *(float4*)&pv[4] = *(const float4*)(pr + 4096 + c + 4);
    *(float4*)&w0[0] = *(const float4*)(cq + i * 2048 + c); *(float4*)&w0[4] = *(const float4*)(cq + i * 2048 + c + 4);
    *(float4*)&w1[0] = *(const float4*)(ck + i * 2048 + c); *(float4*)&w1[4] = *(const float4*)(ck + i * 2048 + c + 4);
    *(float4*)&w2[0] = *(const float4*)(cv + i * 2048 + c); *(float4*)&w2[4] = *(const float4*)(cv + i * 2048 + c + 4);
#pragma unroll
    for (int j = 0; j < 8; j++) { aq[j] += w0[j]*pq[j]; ak[j] += w1[j]*pk[j]; av[j] += w2[j]*pv[j]; }
  }
  float sq[8], sk[8], sv[8]; float ssq = 0.f, ssk = 0.f;
#pragma unroll
  for (int j = 0; j < 8; j++) {
    sq[j] = silu_f(aq[j]); ssq += sq[j]*sq[j];
    sk[j] = silu_f(ak[j]); ssk += sk[j]*sk[j];
    sv[j] = silu_f(av[j]);
  }
  ssq = red16(ssq); ssk = red16(ssk);   // 16 lanes cover one head (128 ch)
  const float rq = rsqrtf(ssq + 1e-6f) * 0.08838834764831845f;  // * DK^-0.5
  const float rk = rsqrtf(ssk + 1e-6f);
  float oq[8], ok[8]; float qkl = 0.f;
#pragma unroll
  for (int j = 0; j < 8; j++) { oq[j] = sq[j]*rq; ok[j] = sk[j]*rk; qkl += oq[j]*ok[j]; }
  qkl = red16(qkl);
  if ((tid & 15) == 0) qkbuf[(size_t)t * 16 + (tid >> 4)] = qkl;
  float* qo = q + (size_t)t * 2048 + c;
  *(float4*)qo = *(float4*)&oq[0]; *(float4*)(qo + 4) = *(float4*)&oq[4];
  float* ko = k + (size_t)t * 2048 + c;
  *(float4*)ko = *(float4*)&ok[0]; *(float4*)(ko + 4) = *(float4*)&ok[4];
  float* vo = v + (size_t)t * 2048 + c;
  *(float4*)vo = *(float4*)&sv[0]; *(float4*)(vo + 4) = *(float4*)&sv[4];
}

// ---------- eg=exp(g), beta, ga->bf16 ----------
__global__ void __launch_bounds__(64) gates_kernel(const float* __restrict__ small,
                                                   const float* __restrict__ wfb,
                                                   const float* __restrict__ a_log,
                                                   const float* __restrict__ dtb,
                                                   float* __restrict__ eg, float* __restrict__ beta,
                                                   unsigned short* __restrict__ gab) {
  const int t = blockIdx.x, tid = threadIdx.x;
  const float* srow = small + (size_t)t * 272;
  if (tid < 16) {
    float d = dtb[tid];
    for (int j = 0; j < 128; j++) d += srow[j] * wfb[j * 16 + tid];
    float sp = (d > 20.f) ? d : log1pf(expf(d));
    eg[t * 16 + tid] = expf(-expf(a_log[tid]) * sp);   // pre-exponentiated decay
    float b = srow[128 + tid];
    beta[t * 16 + tid] = 1.f / (1.f + expf(-b));
  }
  for (int j = tid; j < 128; j += 64) gab[(size_t)t * 128 + j] = f2bf(srow[144 + j]);
}

// ---------- gated delta-rule scan ----------
// one wave = 4 v-columns of one head; 4-slot register prefetch; DPP reductions.
struct Slot { float k[8], q[8], v, eg, bt, qk; };

__device__ __forceinline__ void load_slot(Slot& X, const float* kb, const float* qb,
                                          const float* vb, const float* egb,
                                          const float* btb, const float* qkb, int tt) {
  const float* kp = kb + (size_t)tt * 2048;
  const float* qp = qb + (size_t)tt * 2048;
  float4 a0 = *(const float4*)kp, a1 = *(const float4*)(kp + 4);
  float4 b0 = *(const float4*)qp, b1 = *(const float4*)(qp + 4);
  X.k[0]=a0.x; X.k[1]=a0.y; X.k[2]=a0.z; X.k[3]=a0.w;
  X.k[4]=a1.x; X.k[5]=a1.y; X.k[6]=a1.z; X.k[7]=a1.w;
  X.q[0]=b0.x; X.q[1]=b0.y; X.q[2]=b0.z; X.q[3]=b0.w;
  X.q[4]=b1.x; X.q[5]=b1.y; X.q[6]=b1.z; X.q[7]=b1.w;
  X.v  = vb[(size_t)tt * 2048];
  X.eg = egb[tt * 16];
  X.bt = btb[tt * 16];
  X.qk = qkb[tt * 16];
}

__device__ __forceinline__ void step_slot(const Slot& X, float (&S)[8], float* ob,
                                          bool dostore, int tt) {
  float kS0 = X.k[0]*S[0] + X.k[4]*S[4];
  float kS1 = X.k[1]*S[1] + X.k[5]*S[5];
  float kS2 = X.k[2]*S[2] + X.k[6]*S[6];
  float kS3 = X.k[3]*S[3] + X.k[7]*S[7];
  float qS0 = X.q[0]*S[0] + X.q[4]*S[4];
  float qS1 = X.q[1]*S[1] + X.q[5]*S[5];
  float qS2 = X.q[2]*S[2] + X.q[6]*S[6];
  float qS3 = X.q[3]*S[3] + X.q[7]*S[7];
  float kS = red16d((kS0 + kS1) + (kS2 + kS3));
  float qS = red16d((qS0 + qS1) + (qS2 + qS3));
  float delta = X.bt * (X.v - X.eg * kS);
#pragma unroll
  for (int i = 0; i < 8; i++) S[i] = X.eg * S[i] + X.k[i] * delta;
  if (dostore) ob[(size_t)tt * 2048] = X.eg * qS + X.qk * delta;
}

__global__ void __launch_bounds__(64) scan_kernel(const float* __restrict__ q,
                                                  const float* __restrict__ k,
                                                  const float* __restrict__ v,
                                                  const float* __restrict__ eg,
                                                  const float* __restrict__ beta,
                                                  const float* __restrict__ qkbuf,
                                                  float* __restrict__ o) {
  // XCD swizzle: b&7 = XCD (empirical round-robin) -> heads 2x,2x+1 stay on one XCD
  const int b = blockIdx.x;            // 512 = 16 heads * 32 slices
  const int xcd = b & 7, r = b >> 3;
  const int h = (xcd << 1) | (r >> 5);
  const int vbase = (r & 31) << 2;
  const int lane = threadIdx.x;
  const int kl = lane & 15, vl = lane >> 4;
  const int vcol = vbase + vl;
  const int koff = h * 128 + kl * 8;
  const int voff = h * 128 + vcol;
  const float* kb = k + koff;
  const float* qb = q + koff;
  const float* vb = v + voff;
  const float* egb = eg + h;
  const float* btb = beta + h;
  const float* qkb = qkbuf + h;
  float* ob = o + voff;
  const bool dostore = (kl == 0);
  float S[8] = {0,0,0,0,0,0,0,0};
  Slot A, B, C, D;
  load_slot(A, kb, qb, vb, egb, btb, qkb, 0);
  load_slot(B, kb, qb, vb, egb, btb, qkb, 1);
  load_slot(C, kb, qb, vb, egb, btb, qkb, 2);
  load_slot(D, kb, qb, vb, egb, btb, qkb, 3);
  for (int t = 0; t < 1024; t += 4) {
    step_slot(A, S, ob, dostore, t);
    { int tn = t + 4; if (tn > 1023) tn = 1023; load_slot(A, kb, qb, vb, egb, btb, qkb, tn); }
    step_slot(B, S, ob, dostore, t + 1);
    { int tn = t + 5; if (tn > 1023) tn = 1023; load_slot(B, kb, qb, vb, egb, btb, qkb, tn); }
    step_slot(C, S, ob, dostore, t + 2);
    { int tn = t + 6; if (tn > 1023) tn = 1023; load_slot(C, kb, qb, vb, egb, btb, qkb, tn); }
    step_slot(D, S, ob, dostore, t + 3);
    { int tn = t + 7; if (tn > 1023) tn = 1023; load_slot(D, kb, qb, vb, egb, btb, qkb, tn); }
  }
}

// ---------- o_gated = bf16(rmsnorm_head(o)*w * silu(gate)) ----------
__global__ void __launch_bounds__(256) gate_o_kernel(const float* __restrict__ o,
                                                     const float* __restrict__ gate,
                                                     const float* __restrict__ onw,
                                                     unsigned short* __restrict__ ogb) {
  const int t = blockIdx.x, tid = threadIdx.x;
  const int c = tid << 3;
  const float* orow = o + (size_t)t * 2048 + c;
  float ov[8]; *(float4*)&ov[0] = *(const float4*)orow; *(float4*)&ov[4] = *(const float4*)(orow + 4);
  float ss = 0.f;
#pragma unroll
  for (int j = 0; j < 8; j++) ss += ov[j] * ov[j];
  ss = red16(ss);
  const float rn = rsqrtf(ss * (1.f / 128.f) + 1e-6f);
  const int dv = (tid & 15) << 3;
  float wv[8]; *(float4*)&wv[0] = *(const float4*)(onw + dv); *(float4*)&wv[4] = *(const float4*)(onw + dv + 4);
  const float* grow = gate + (size_t)t * 2048 + c;
  float gv[8]; *(float4*)&gv[0] = *(const float4*)grow; *(float4*)&gv[4] = *(const float4*)(grow + 4);
  u16x8 r;
#pragma unroll
  for (int j = 0; j < 8; j++) r[j] = f2bf(ov[j] * rn * wv[j] * silu_f(gv[j]));
  *(u16x8*)(ogb + (size_t)t * 2048 + c) = r;
}

// ---------- swiglu: mid = bf16(silu(m1[:, :8192]) * m1[:, 8192:]) ----------
__global__ void swiglu_kernel(const float* __restrict__ m1, unsigned short* __restrict__ mid) {
  const int NU = 1024 * 2048;  // units of 4 along I
  for (int u = blockIdx.x * blockDim.x + threadIdx.x; u < NU; u += gridDim.x * blockDim.x) {
    const int t = u >> 11;
    const int j4 = (u & 2047) << 2;
    const float* base = m1 + (size_t)t * 16384;
    float4 gv = *(const float4*)(base + j4);
    float4 uv = *(const float4*)(base + 8192 + j4);
    u16x4 r;
    r[0] = f2bf(silu_f(gv.x) * uv.x);
    r[1] = f2bf(silu_f(gv.y) * uv.y);
    r[2] = f2bf(silu_f(gv.z) * uv.z);
    r[3] = f2bf(silu_f(gv.w) * uv.w);
    *(u16x4*)(mid + (size_t)t * 8192 + j4) = r;
  }
}

// ---------- out = a + b ----------
__global__ void final_add_kernel(const float* __restrict__ a, const float* __restrict__ b,
                                 float* __restrict__ out) {
  const int NU = 1024 * 512;
  for (int u = blockIdx.x * blockDim.x + threadIdx.x; u < NU; u += gridDim.x * blockDim.x) {
    float4 va = ((const float4*)a)[u];
    float4 vb = ((const float4*)b)[u];
    va.x += vb.x; va.y += vb.y; va.z += vb.z; va.w += vb.w;
    ((float4*)out)[u] = va;
  }
}

// ---------- ws layout (bytes) ----------
constexpr size_t SZ_WQKVT   = (size_t)6144 * 2048 * 2;
constexpr size_t SZ_WSMALLT = (size_t)272 * 2048 * 2;
constexpr size_t SZ_WGBT    = (size_t)2048 * 128 * 2;
constexpr size_t SZ_WOT     = (size_t)2048 * 2048 * 2;
constexpr size_t SZ_WMLP1T  = (size_t)16384 * 2048 * 2;
constexpr size_t SZ_WDOWNT  = (size_t)2048 * 8192 * 2;
constexpr size_t OFF_WQKVT   = 0;
constexpr size_t OFF_WSMALLT = OFF_WQKVT + SZ_WQKVT;
constexpr size_t OFF_WGBT    = OFF_WSMALLT + SZ_WSMALLT;
constexpr size_t OFF_WOT     = OFF_WGBT + SZ_WGBT;
constexpr size_t OFF_WMLP1T  = OFF_WOT + SZ_WOT;
constexpr size_t OFF_WDOWNT  = OFF_WMLP1T + SZ_WMLP1T;
constexpr size_t A0          = OFF_WDOWNT + SZ_WDOWNT;
constexpr size_t OFF_HB    = A0;
constexpr size_t OFF_PROJ  = OFF_HB + (size_t)1024 * 2048 * 2;
constexpr size_t OFF_SMALL = OFF_PROJ + (size_t)1024 * 6144 * 4;
constexpr size_t OFF_Q     = OFF_SMALL + (size_t)1024 * 272 * 4;
constexpr size_t OFF_K     = OFF_Q + (size_t)1024 * 2048 * 4;
constexpr size_t OFF_V     = OFF_K + (size_t)1024 * 2048 * 4;
constexpr size_t OFF_G     = OFF_V + (size_t)1024 * 2048 * 4;
constexpr size_t OFF_BETA  = OFF_G + (size_t)1024 * 16 * 4;
constexpr size_t OFF_GAB   = OFF_BETA + (size_t)1024 * 16 * 4;
constexpr size_t OFF_GATE  = OFF_GAB + (size_t)1024 * 128 * 2;
constexpr size_t OFF_O     = OFF_GATE + (size_t)1024 * 2048 * 4;
constexpr size_t OFF_OGB   = OFF_O + (size_t)1024 * 2048 * 4;
constexpr size_t OFF_OPROJ = OFF_OGB + (size_t)1024 * 2048 * 2;
constexpr size_t OFF_X1    = OFF_OPROJ + (size_t)1024 * 2048 * 4;
constexpr size_t OFF_H2B   = OFF_X1 + (size_t)1024 * 2048 * 4;
constexpr size_t OFF_MLP1   = A0;
constexpr size_t OFF_MID    = A0 + (size_t)1024 * 16384 * 4;
constexpr size_t OFF_MLPOUT = OFF_H2B + (size_t)1024 * 2048 * 2;
constexpr size_t OFF_QKB    = OFF_MLPOUT + (size_t)1024 * 2048 * 4;   // [1024][16] f32
constexpr size_t WS_NEED    = OFF_QKB + (size_t)1024 * 16 * 4;

extern "C" void kernel_launch(void* const* d_in, const int* in_sizes, int n_in,
                              void* d_out, int out_size, void* d_ws, size_t ws_size,
                              hipStream_t stream) {
  (void)in_sizes; (void)n_in; (void)out_size;
  const float* x     = (const float*)d_in[0];
  const float* wq    = (const float*)d_in[1];
  const float* wk    = (const float*)d_in[2];
  const float* wv    = (const float*)d_in[3];
  const float* cq    = (const float*)d_in[4];
  const float* ck    = (const float*)d_in[5];
  const float* cv    = (const float*)d_in[6];
  const float* wfa   = (const float*)d_in[7];
  const float* wfb   = (const float*)d_in[8];
  const float* wb    = (const float*)d_in[9];
  const float* wga   = (const float*)d_in[10];
  const float* wgb   = (const float*)d_in[11];
  const float* a_log = (const float*)d_in[12];
  const float* dtb   = (const float*)d_in[13];
  const float* onw   = (const float*)d_in[14];
  const float* wo    = (const float*)d_in[15];
  const float* ln1   = (const float*)d_in[16];
  const float* ln2   = (const float*)d_in[17];
  const float* wgate = (const float*)d_in[18];
  const float* wup   = (const float*)d_in[19];
  const float* wdown = (const float*)d_in[20];
  float* out = (float*)d_out;
  char* ws = (char*)d_ws;
  if (ws_size < WS_NEED) return;

  unsigned short* wqkvT   = (unsigned short*)(ws + OFF_WQKVT);
  unsigned short* wsmallT = (unsigned short*)(ws + OFF_WSMALLT);
  unsigned short* wgbT    = (unsigned short*)(ws + OFF_WGBT);
  unsigned short* woT     = (unsigned short*)(ws + OFF_WOT);
  unsigned short* wmlp1T  = (unsigned short*)(ws + OFF_WMLP1T);
  unsigned short* wdownT  = (unsigned short*)(ws + OFF_WDOWNT);
  unsigned short* hb      = (unsigned short*)(ws + OFF_HB);
  float* projf  = (float*)(ws + OFF_PROJ);
  float* smallf = (float*)(ws + OFF_SMALL);
  float* qf     = (float*)(ws + OFF_Q);
  float* kf     = (float*)(ws + OFF_K);
  float* vf     = (float*)(ws + OFF_V);
  float* egf    = (float*)(ws + OFF_G);
  float* betaf  = (float*)(ws + OFF_BETA);
  unsigned short* gab = (unsigned short*)(ws + OFF_GAB);
  float* gatef  = (float*)(ws + OFF_GATE);
  float* of     = (float*)(ws + OFF_O);
  unsigned short* ogb = (unsigned short*)(ws + OFF_OGB);
  float* oprojf = (float*)(ws + OFF_OPROJ);
  float* x1f    = (float*)(ws + OFF_X1);
  unsigned short* h2b = (unsigned short*)(ws + OFF_H2B);
  float* mlp1f  = (float*)(ws + OFF_MLP1);
  unsigned short* midb = (unsigned short*)(ws + OFF_MID);
  float* mlpoutf = (float*)(ws + OFF_MLPOUT);
  float* qkbuf  = (float*)(ws + OFF_QKB);

  trans_kernel<<<dim3(64, 64), 256, 0, stream>>>(wq, wqkvT, 2048, 2048);
  trans_kernel<<<dim3(64, 64), 256, 0, stream>>>(wk, wqkvT + (size_t)2048 * 2048, 2048, 2048);
  trans_kernel<<<dim3(64, 64), 256, 0, stream>>>(wv, wqkvT + (size_t)4096 * 2048, 2048, 2048);
  trans_kernel<<<dim3(4, 64), 256, 0, stream>>>(wfa, wsmallT, 2048, 128);
  trans_kernel<<<dim3(1, 64), 256, 0, stream>>>(wb, wsmallT + (size_t)128 * 2048, 2048, 16);
  trans_kernel<<<dim3(4, 64), 256, 0, stream>>>(wga, wsmallT + (size_t)144 * 2048, 2048, 128);
  trans_kernel<<<dim3(64, 4), 256, 0, stream>>>(wgb, wgbT, 128, 2048);
  trans_kernel<<<dim3(64, 64), 256, 0, stream>>>(wo, woT, 2048, 2048);
  trans_kernel<<<dim3(256, 64), 256, 0, stream>>>(wgate, wmlp1T, 2048, 8192);
  trans_kernel<<<dim3(256, 64), 256, 0, stream>>>(wup, wmlp1T + (size_t)8192 * 2048, 2048, 8192);
  trans_kernel<<<dim3(64, 256), 256, 0, stream>>>(wdown, wdownT, 8192, 2048);

  rmsnorm_bf16_kernel<<<1024, 256, 0, stream>>>(x, ln1, hb);
  gemm_bt_kernel<<<dim3(8, 48), 256, 0, stream>>>(hb, wqkvT, projf, 1024, 6144, 2048);
  gemm_bt_kernel<<<dim3(8, 3), 256, 0, stream>>>(hb, wsmallT, smallf, 1024, 272, 2048);
  conv_kernel<<<1024, 256, 0, stream>>>(projf, cq, ck, cv, qf, kf, vf, qkbuf);
  gates_kernel<<<1024, 64, 0, stream>>>(smallf, wfb, a_log, dtb, egf, betaf, gab);
  gemm_bt_kernel<<<dim3(8, 16), 256, 0, stream>>>(gab, wgbT, gatef, 1024, 2048, 128);
  scan_kernel<<<512, 64, 0, stream>>>(qf, kf, vf, egf, betaf, qkbuf, of);
  gate_o_kernel<<<1024, 256, 0, stream>>>(of, gatef, onw, ogb);
  gemm_bt_kernel<<<dim3(8, 16), 256, 0, stream>>>(ogb, woT, oprojf, 1024, 2048, 2048);
  add_rmsnorm_kernel<<<1024, 256, 0, stream>>>(x, oprojf, ln2, x1f, h2b);
  gemm_bt_kernel<<<dim3(8, 128), 256, 0, stream>>>(h2b, wmlp1T, mlp1f, 1024, 16384, 2048);
  swiglu_kernel<<<2048, 256, 0, stream>>>(mlp1f, midb);
  gemm_bt_kernel<<<dim3(8, 16), 256, 0, stream>>>(midb, wdownT, mlpoutf, 1024, 2048, 8192);
  final_add_kernel<<<2048, 256, 0, stream>>>(x1f, mlpoutf, out);
}

// Round 3
// 917.399 us; speedup vs baseline: 1.3226x; 1.1068x over previous
//
#include <hip/hip_runtime.h>
#include <hip/hip_bf16.h>

typedef __attribute__((ext_vector_type(8))) short short8;
typedef __attribute__((ext_vector_type(4))) float f32x4;
typedef __attribute__((ext_vector_type(8))) unsigned short u16x8;
typedef __attribute__((ext_vector_type(4))) unsigned short u16x4;

// ---------- helpers ----------
__device__ __forceinline__ unsigned short f2bf(float f) {
  unsigned u = __float_as_uint(f);
  u += 0x7fffu + ((u >> 16) & 1u);          // round-to-nearest-even
  return (unsigned short)(u >> 16);
}
__device__ __forceinline__ float silu_f(float x) { return x / (1.f + __expf(-x)); }
__device__ __forceinline__ float red16(float v) {  // sum across 16-lane group (shfl)
  v += __shfl_xor(v, 1); v += __shfl_xor(v, 2);
  v += __shfl_xor(v, 4); v += __shfl_xor(v, 8);
  return v;
}
// DPP 16-lane sum: quad xor1, quad xor2, half-mirror, row-mirror
template <int CTRL>
__device__ __forceinline__ float dpp_mv(float v) {
  return __int_as_float(__builtin_amdgcn_update_dpp(0, __float_as_int(v), CTRL, 0xF, 0xF, true));
}
__device__ __forceinline__ float red16d(float v) {
  v += dpp_mv<0xB1>(v);   // quad_perm [1,0,3,2]
  v += dpp_mv<0x4E>(v);   // quad_perm [2,3,0,1]
  v += dpp_mv<0x141>(v);  // row_half_mirror
  v += dpp_mv<0x140>(v);  // row_mirror
  return v;
}
__device__ __forceinline__ void gload16(const void* g, void* l) {
  __builtin_amdgcn_global_load_lds((const __attribute__((address_space(1))) void*)g,
                                   (__attribute__((address_space(3))) void*)l, 16, 0, 0);
}

// ---------- transpose fp32 [R][C] -> bf16 [C][R] ----------
__global__ void __launch_bounds__(256) trans_kernel(const float* __restrict__ src,
                                                    unsigned short* __restrict__ dst,
                                                    int R, int C) {
  __shared__ float tile[32][33];
  const int tx = threadIdx.x & 31, ty = threadIdx.x >> 5;
  const int c = blockIdx.x * 32 + tx;
#pragma unroll
  for (int i = 0; i < 32; i += 8) {
    int r = blockIdx.y * 32 + ty + i;
    if (r < R && c < C) tile[ty + i][tx] = src[(size_t)r * C + c];
  }
  __syncthreads();
  const int rc = blockIdx.y * 32 + tx;
#pragma unroll
  for (int i = 0; i < 32; i += 8) {
    int cc = blockIdx.x * 32 + ty + i;
    if (cc < C && rc < R) dst[(size_t)cc * R + rc] = f2bf(tile[tx][ty + i]);
  }
}

// ---------- rmsnorm (D=2048) -> bf16 ----------
__global__ void __launch_bounds__(256) rmsnorm_bf16_kernel(const float* __restrict__ x,
                                                           const float* __restrict__ w,
                                                           unsigned short* __restrict__ outb) {
  const int t = blockIdx.x, tid = threadIdx.x;
  const float* xr = x + (size_t)t * 2048 + tid * 8;
  float4 v0 = *(const float4*)xr, v1 = *(const float4*)(xr + 4);
  float ss = v0.x*v0.x + v0.y*v0.y + v0.z*v0.z + v0.w*v0.w
           + v1.x*v1.x + v1.y*v1.y + v1.z*v1.z + v1.w*v1.w;
#pragma unroll
  for (int m = 1; m < 64; m <<= 1) ss += __shfl_xor(ss, m);
  __shared__ float sb[4];
  if ((tid & 63) == 0) sb[tid >> 6] = ss;
  __syncthreads();
  float rn = rsqrtf((sb[0] + sb[1] + sb[2] + sb[3]) * (1.f / 2048.f) + 1e-6f);
  const float* wr = w + tid * 8;
  float4 w0 = *(const float4*)wr, w1 = *(const float4*)(wr + 4);
  u16x8 r;
  r[0]=f2bf(v0.x*rn*w0.x); r[1]=f2bf(v0.y*rn*w0.y); r[2]=f2bf(v0.z*rn*w0.z); r[3]=f2bf(v0.w*rn*w0.w);
  r[4]=f2bf(v1.x*rn*w1.x); r[5]=f2bf(v1.y*rn*w1.y); r[6]=f2bf(v1.z*rn*w1.z); r[7]=f2bf(v1.w*rn*w1.w);
  *(u16x8*)(outb + (size_t)t * 2048 + tid * 8) = r;
}

// ---------- x1 = x + y ; h2b = bf16(rmsnorm(x1)*w) ----------
__global__ void __launch_bounds__(256) add_rmsnorm_kernel(const float* __restrict__ x,
                                                          const float* __restrict__ y,
                                                          const float* __restrict__ w,
                                                          float* __restrict__ x1,
                                                          unsigned short* __restrict__ h2b) {
  const int t = blockIdx.x, tid = threadIdx.x;
  const int c = tid * 8;
  const float* xr = x + (size_t)t * 2048 + c;
  const float* yr = y + (size_t)t * 2048 + c;
  float s[8]; float ss = 0.f;
  float4 a0 = *(const float4*)xr, a1 = *(const float4*)(xr + 4);
  float4 b0 = *(const float4*)yr, b1 = *(const float4*)(yr + 4);
  s[0]=a0.x+b0.x; s[1]=a0.y+b0.y; s[2]=a0.z+b0.z; s[3]=a0.w+b0.w;
  s[4]=a1.x+b1.x; s[5]=a1.y+b1.y; s[6]=a1.z+b1.z; s[7]=a1.w+b1.w;
#pragma unroll
  for (int j = 0; j < 8; j++) ss += s[j] * s[j];
#pragma unroll
  for (int m = 1; m < 64; m <<= 1) ss += __shfl_xor(ss, m);
  __shared__ float sb[4];
  if ((tid & 63) == 0) sb[tid >> 6] = ss;
  __syncthreads();
  float rn = rsqrtf((sb[0] + sb[1] + sb[2] + sb[3]) * (1.f / 2048.f) + 1e-6f);
  float* xo = x1 + (size_t)t * 2048 + c;
  *(float4*)xo = *(float4*)&s[0];
  *(float4*)(xo + 4) = *(float4*)&s[4];
  const float* wr = w + c;
  float4 w0 = *(const float4*)wr, w1 = *(const float4*)(wr + 4);
  float wv[8] = {w0.x,w0.y,w0.z,w0.w,w1.x,w1.y,w1.z,w1.w};
  u16x8 r;
#pragma unroll
  for (int j = 0; j < 8; j++) r[j] = f2bf(s[j] * rn * wv[j]);
  *(u16x8*)(h2b + (size_t)t * 2048 + c) = r;
}

// ---------- bf16 GEMM: C[M,N] = A[M,K] * Bt[N,K]^T  (m97-style, strided) ----------
__global__ void __launch_bounds__(256) gemm_bt_kernel(const unsigned short* __restrict__ A,
                                                      const unsigned short* __restrict__ Bt,
                                                      float* __restrict__ C,
                                                      int M, int N, int K, int lda, int ldb) {
  __shared__ unsigned short As[128][32];
  __shared__ unsigned short Bs[128][32];
  const int tid = threadIdx.x;
  const int m0 = blockIdx.x << 7, n0 = blockIdx.y << 7;
  const int wave = tid >> 6, lane = tid & 63;
  const int wm = (wave >> 1) << 6, wn = (wave & 1) << 6;
  const int lrow = lane >> 2, lcol = lane & 3;
  const int ar0 = wave * 16 + lrow;
  const int ar1 = ar0 + 64;
  int br0 = n0 + ar0; br0 = br0 < N ? br0 : N - 1;
  int br1 = n0 + ar1; br1 = br1 < N ? br1 : N - 1;
  const unsigned short* Aptr0 = A + (size_t)(m0 + ar0) * lda + ((lcol ^ (ar0 & 3)) << 3);
  const unsigned short* Aptr1 = A + (size_t)(m0 + ar1) * lda + ((lcol ^ (ar1 & 3)) << 3);
  const unsigned short* Bptr0 = Bt + (size_t)br0 * ldb + ((lcol ^ (ar0 & 3)) << 3);
  const unsigned short* Bptr1 = Bt + (size_t)br1 * ldb + ((lcol ^ (ar1 & 3)) << 3);
  unsigned short* lA0 = &As[wave * 16][0];
  unsigned short* lA1 = &As[64 + wave * 16][0];
  unsigned short* lB0 = &Bs[wave * 16][0];
  unsigned short* lB1 = &Bs[64 + wave * 16][0];
  const int frow = lane & 15, fkb = lane >> 4;
  f32x4 acc[4][4];
#pragma unroll
  for (int i = 0; i < 4; i++)
#pragma unroll
    for (int j = 0; j < 4; j++) acc[i][j] = (f32x4){0.f, 0.f, 0.f, 0.f};

  for (int k0 = 0; k0 < K; k0 += 32) {
    gload16(Aptr0 + k0, lA0);
    gload16(Aptr1 + k0, lA1);
    gload16(Bptr0 + k0, lB0);
    gload16(Bptr1 + k0, lB1);
    __syncthreads();
    short8 af[4], bfr[4];
#pragma unroll
    for (int i = 0; i < 4; i++) {
      int ra = wm + i * 16 + frow;
      af[i] = *(const short8*)&As[ra][(fkb ^ (ra & 3)) << 3];
      int rb = wn + i * 16 + frow;
      bfr[i] = *(const short8*)&Bs[rb][(fkb ^ (rb & 3)) << 3];
    }
#pragma unroll
    for (int i = 0; i < 4; i++)
#pragma unroll
      for (int j = 0; j < 4; j++)
        acc[i][j] = __builtin_amdgcn_mfma_f32_16x16x32_bf16(af[i], bfr[j], acc[i][j], 0, 0, 0);
    __syncthreads();
  }
  const int crow = (lane >> 4) << 2, ccol = lane & 15;
#pragma unroll
  for (int i = 0; i < 4; i++) {
    const int gr = m0 + wm + i * 16 + crow;
#pragma unroll
    for (int j = 0; j < 4; j++) {
      const int gc = n0 + wn + j * 16 + ccol;
      if (gc < N) {
#pragma unroll
        for (int r = 0; r < 4; r++) C[(size_t)(gr + r) * N + gc] = acc[i][j][r];
      }
    }
  }
}

// ---------- causal dwconv(K=4) + silu + per-head l2norm + qk dot ----------
__global__ void __launch_bounds__(256) conv_kernel(const float* __restrict__ proj,
                                                   const float* __restrict__ cq,
                                                   const float* __restrict__ ck,
                                                   const float* __restrict__ cv,
                                                   float* __restrict__ q, float* __restrict__ k,
                                                   float* __restrict__ v,
                                                   float* __restrict__ qkbuf) {
  const int t = blockIdx.x, tid = threadIdx.x;
  const int c = tid << 3;
  float aq[8] = {0,0,0,0,0,0,0,0}, ak[8] = {0,0,0,0,0,0,0,0}, av[8] = {0,0,0,0,0,0,0,0};
#pragma unroll
  for (int i = 0; i < 4; i++) {
    const int tt = t + i - 3;
    if (tt < 0) continue;
    const float* pr = proj + (size_t)tt * 6144;
    float pq[8], pk[8], pv[8], w0[8], w1[8], w2[8];
    *(float4*)&pq[0] = *(const float4*)(pr + c);        *(float4*)&pq[4] = *(const float4*)(pr + c + 4);
    *(float4*)&pk[0] = *(const float4*)(pr + 2048 + c); *(float4*)&pk[4] = *(const float4*)(pr + 2048 + c + 4);
    *(float4*)&pv[0] = *(const float4*)(pr + 4096 + c); *(float4*)&pv[4] = *(const float4*)(pr + 4096 + c + 4);
    *(float4*)&w0[0] = *(const float4*)(cq + i * 2048 + c); *(float4*)&w0[4] = *(const float4*)(cq + i * 2048 + c + 4);
    *(float4*)&w1[0] = *(const float4*)(ck + i * 2048 + c); *(float4*)&w1[4] = *(const float4*)(ck + i * 2048 + c + 4);
    *(float4*)&w2[0] = *(const float4*)(cv + i * 2048 + c); *(float4*)&w2[4] = *(const float4*)(cv + i * 2048 + c + 4);
#pragma unroll
    for (int j = 0; j < 8; j++) { aq[j] += w0[j]*pq[j]; ak[j] += w1[j]*pk[j]; av[j] += w2[j]*pv[j]; }
  }
  float sq[8], sk[8], sv[8]; float ssq = 0.f, ssk = 0.f;
#pragma unroll
  for (int j = 0; j < 8; j++) {
    sq[j] = silu_f(aq[j]); ssq += sq[j]*sq[j];
    sk[j] = silu_f(ak[j]); ssk += sk[j]*sk[j];
    sv[j] = silu_f(av[j]);
  }
  ssq = red16(ssq); ssk = red16(ssk);   // 16 lanes cover one head (128 ch)
  const float rq = rsqrtf(ssq + 1e-6f) * 0.08838834764831845f;  // * DK^-0.5
  const float rk = rsqrtf(ssk + 1e-6f);
  float oq[8], ok[8]; float qkl = 0.f;
#pragma unroll
  for (int j = 0; j < 8; j++) { oq[j] = sq[j]*rq; ok[j] = sk[j]*rk; qkl += oq[j]*ok[j]; }
  qkl = red16(qkl);
  if ((tid & 15) == 0) qkbuf[(size_t)t * 16 + (tid >> 4)] = qkl;
  float* qo = q + (size_t)t * 2048 + c;
  *(float4*)qo = *(float4*)&oq[0]; *(float4*)(qo + 4) = *(float4*)&oq[4];
  float* ko = k + (size_t)t * 2048 + c;
  *(float4*)ko = *(float4*)&ok[0]; *(float4*)(ko + 4) = *(float4*)&ok[4];
  float* vo = v + (size_t)t * 2048 + c;
  *(float4*)vo = *(float4*)&sv[0]; *(float4*)(vo + 4) = *(float4*)&sv[4];
}

// ---------- packed gates: g4[t][h] = (eg, beta, qk, 0); gab->bf16 ----------
__global__ void __launch_bounds__(64) gates_kernel(const float* __restrict__ small,
                                                   const float* __restrict__ wfb,
                                                   const float* __restrict__ a_log,
                                                   const float* __restrict__ dtb,
                                                   const float* __restrict__ qkbuf,
                                                   float4* __restrict__ g4,
                                                   unsigned short* __restrict__ gab) {
  const int t = blockIdx.x, tid = threadIdx.x;
  const float* srow = small + (size_t)t * 272;
  if (tid < 16) {
    float d = dtb[tid];
    for (int j = 0; j < 128; j++) d += srow[j] * wfb[j * 16 + tid];
    float sp = (d > 20.f) ? d : log1pf(expf(d));
    float eg = expf(-expf(a_log[tid]) * sp);
    float b = srow[128 + tid];
    float bt = 1.f / (1.f + expf(-b));
    g4[t * 16 + tid] = make_float4(eg, bt, qkbuf[t * 16 + tid], 0.f);
  }
  for (int j = tid; j < 128; j += 64) gab[(size_t)t * 128 + j] = f2bf(srow[144 + j]);
}

// ---------- gated delta-rule scan ----------
// one wave = 4 v-columns of one head; 8 named prefetch slots; DPP reductions.
struct Slot { float4 k0, k1, q0, q1; float eg, qk, btv, bteg; };

__device__ __forceinline__ void load_slot(Slot& X, const float* kb, const float* qb,
                                          const float* vb, const float4* g4b, int tt) {
  const float* kp = kb + (size_t)tt * 2048;
  const float* qp = qb + (size_t)tt * 2048;
  X.k0 = *(const float4*)kp; X.k1 = *(const float4*)(kp + 4);
  X.q0 = *(const float4*)qp; X.q1 = *(const float4*)(qp + 4);
  float4 g = g4b[(size_t)tt * 16];
  float v = vb[(size_t)tt * 2048];
  X.eg = g.x; X.qk = g.z;
  X.btv = g.y * v;            // off-chain precompute
  X.bteg = g.y * g.x;
}

__device__ __forceinline__ void step_slot(const Slot& X, float (&S)[8], float* ob,
                                          bool dostore, int tt) {
  float a0 = fmaf(X.k1.x, S[4], X.k0.x * S[0]);
  float a1 = fmaf(X.k1.y, S[5], X.k0.y * S[1]);
  float a2 = fmaf(X.k1.z, S[6], X.k0.z * S[2]);
  float a3 = fmaf(X.k1.w, S[7], X.k0.w * S[3]);
  float b0 = fmaf(X.q1.x, S[4], X.q0.x * S[0]);
  float b1 = fmaf(X.q1.y, S[5], X.q0.y * S[1]);
  float b2 = fmaf(X.q1.z, S[6], X.q0.z * S[2]);
  float b3 = fmaf(X.q1.w, S[7], X.q0.w * S[3]);
  float kS = red16d((a0 + a1) + (a2 + a3));
  float qS = red16d((b0 + b1) + (b2 + b3));
  float delta = fmaf(-X.bteg, kS, X.btv);   // bt*(v - eg*kS)
  S[0] = fmaf(X.k0.x, delta, X.eg * S[0]);
  S[1] = fmaf(X.k0.y, delta, X.eg * S[1]);
  S[2] = fmaf(X.k0.z, delta, X.eg * S[2]);
  S[3] = fmaf(X.k0.w, delta, X.eg * S[3]);
  S[4] = fmaf(X.k1.x, delta, X.eg * S[4]);
  S[5] = fmaf(X.k1.y, delta, X.eg * S[5]);
  S[6] = fmaf(X.k1.z, delta, X.eg * S[6]);
  S[7] = fmaf(X.k1.w, delta, X.eg * S[7]);
  if (dostore) ob[(size_t)tt * 2048] = fmaf(X.qk, delta, X.eg * qS);
}

__global__ void __launch_bounds__(64, 1) scan_kernel(const float* __restrict__ q,
                                                     const float* __restrict__ k,
                                                     const float* __restrict__ v,
                                                     const float4* __restrict__ g4,
                                                     float* __restrict__ o) {
  // XCD swizzle: b&7 = XCD -> heads 2x,2x+1 stay on one XCD
  const int b = blockIdx.x;            // 512 = 16 heads * 32 slices
  const int xcd = b & 7, r = b >> 3;
  const int h = (xcd << 1) | (r >> 5);
  const int vbase = (r & 31) << 2;
  const int lane = threadIdx.x;
  const int kl = lane & 15, vl = lane >> 4;
  const int vcol = vbase + vl;
  const int koff = h * 128 + kl * 8;
  const int voff = h * 128 + vcol;
  const float* kb = k + koff;
  const float* qb = q + koff;
  const float* vb = v + voff;
  const float4* g4b = g4 + h;
  float* ob = o + voff;
  const bool dostore = (kl == 0);
  float S[8] = {0,0,0,0,0,0,0,0};
  Slot s0, s1, s2, s3, s4, s5, s6, s7;
  load_slot(s0, kb, qb, vb, g4b, 0);
  load_slot(s1, kb, qb, vb, g4b, 1);
  load_slot(s2, kb, qb, vb, g4b, 2);
  load_slot(s3, kb, qb, vb, g4b, 3);
  load_slot(s4, kb, qb, vb, g4b, 4);
  load_slot(s5, kb, qb, vb, g4b, 5);
  load_slot(s6, kb, qb, vb, g4b, 6);
  load_slot(s7, kb, qb, vb, g4b, 7);
  // NOTE: prefetch reads past t=1023 land in adjacent ws regions (in-bounds,
  // never consumed) -- no clamp on the critical path.
  for (int t = 0; t < 1024; t += 8) {
    step_slot(s0, S, ob, dostore, t + 0); load_slot(s0, kb, qb, vb, g4b, t + 8);
    step_slot(s1, S, ob, dostore, t + 1); load_slot(s1, kb, qb, vb, g4b, t + 9);
    step_slot(s2, S, ob, dostore, t + 2); load_slot(s2, kb, qb, vb, g4b, t + 10);
    step_slot(s3, S, ob, dostore, t + 3); load_slot(s3, kb, qb, vb, g4b, t + 11);
    step_slot(s4, S, ob, dostore, t + 4); load_slot(s4, kb, qb, vb, g4b, t + 12);
    step_slot(s5, S, ob, dostore, t + 5); load_slot(s5, kb, qb, vb, g4b, t + 13);
    step_slot(s6, S, ob, dostore, t + 6); load_slot(s6, kb, qb, vb, g4b, t + 14);
    step_slot(s7, S, ob, dostore, t + 7); load_slot(s7, kb, qb, vb, g4b, t + 15);
  }
}

// ---------- o_gated = bf16(rmsnorm_head(o)*w * silu(gate)) ----------
__global__ void __launch_bounds__(256) gate_o_kernel(const float* __restrict__ o,
                                                     const float* __restrict__ gate,
                                                     const float* __restrict__ onw,
                                                     unsigned short* __restrict__ ogb) {
  const int t = blockIdx.x, tid = threadIdx.x;
  const int c = tid << 3;
  const float* orow = o + (size_t)t * 2048 + c;
  float ov[8]; *(float4*)&ov[0] = *(const float4*)orow; *(float4*)&ov[4] = *(const float4*)(orow + 4);
  float ss = 0.f;
#pragma unroll
  for (int j = 0; j < 8; j++) ss += ov[j] * ov[j];
  ss = red16(ss);
  const float rn = rsqrtf(ss * (1.f / 128.f) + 1e-6f);
  const int dv = (tid & 15) << 3;
  float wv[8]; *(float4*)&wv[0] = *(const float4*)(onw + dv); *(float4*)&wv[4] = *(const float4*)(onw + dv + 4);
  const float* grow = gate + (size_t)t * 2048 + c;
  float gv[8]; *(float4*)&gv[0] = *(const float4*)grow; *(float4*)&gv[4] = *(const float4*)(grow + 4);
  u16x8 r;
#pragma unroll
  for (int j = 0; j < 8; j++) r[j] = f2bf(ov[j] * rn * wv[j] * silu_f(gv[j]));
  *(u16x8*)(ogb + (size_t)t * 2048 + c) = r;
}

// ---------- swiglu ----------
__global__ void swiglu_kernel(const float* __restrict__ m1, unsigned short* __restrict__ mid) {
  const int NU = 1024 * 2048;
  for (int u = blockIdx.x * blockDim.x + threadIdx.x; u < NU; u += gridDim.x * blockDim.x) {
    const int t = u >> 11;
    const int j4 = (u & 2047) << 2;
    const float* base = m1 + (size_t)t * 16384;
    float4 gv = *(const float4*)(base + j4);
    float4 uv = *(const float4*)(base + 8192 + j4);
    u16x4 r;
    r[0] = f2bf(silu_f(gv.x) * uv.x);
    r[1] = f2bf(silu_f(gv.y) * uv.y);
    r[2] = f2bf(silu_f(gv.z) * uv.z);
    r[3] = f2bf(silu_f(gv.w) * uv.w);
    *(u16x4*)(mid + (size_t)t * 8192 + j4) = r;
  }
}

// ---------- out = a + b + c (split-K down-proj) ----------
__global__ void final_add3_kernel(const float* __restrict__ a, const float* __restrict__ b,
                                  const float* __restrict__ c, float* __restrict__ out) {
  const int NU = 1024 * 512;
  for (int u = blockIdx.x * blockDim.x + threadIdx.x; u < NU; u += gridDim.x * blockDim.x) {
    float4 va = ((const float4*)a)[u];
    float4 vb = ((const float4*)b)[u];
    float4 vc = ((const float4*)c)[u];
    va.x += vb.x + vc.x; va.y += vb.y + vc.y; va.z += vb.z + vc.z; va.w += vb.w + vc.w;
    ((float4*)out)[u] = va;
  }
}

// ---------- ws layout (bytes) ----------
constexpr size_t SZ_WQKVT   = (size_t)6144 * 2048 * 2;
constexpr size_t SZ_WSMALLT = (size_t)272 * 2048 * 2;
constexpr size_t SZ_WGBT    = (size_t)2048 * 128 * 2;
constexpr size_t SZ_WOT     = (size_t)2048 * 2048 * 2;
constexpr size_t SZ_WMLP1T  = (size_t)16384 * 2048 * 2;
constexpr size_t SZ_WDOWNT  = (size_t)2048 * 8192 * 2;
constexpr size_t OFF_WQKVT   = 0;
constexpr size_t OFF_WSMALLT = OFF_WQKVT + SZ_WQKVT;
constexpr size_t OFF_WGBT    = OFF_WSMALLT + SZ_WSMALLT;
constexpr size_t OFF_WOT     = OFF_WGBT + SZ_WGBT;
constexpr size_t OFF_WMLP1T  = OFF_WOT + SZ_WOT;
constexpr size_t OFF_WDOWNT  = OFF_WMLP1T + SZ_WMLP1T;
constexpr size_t A0          = OFF_WDOWNT + SZ_WDOWNT;
constexpr size_t OFF_HB    = A0;
constexpr size_t OFF_PROJ  = OFF_HB + (size_t)1024 * 2048 * 2;
constexpr size_t OFF_SMALL = OFF_PROJ + (size_t)1024 * 6144 * 4;
constexpr size_t OFF_Q     = OFF_SMALL + (size_t)1024 * 272 * 4;
constexpr size_t OFF_K     = OFF_Q + (size_t)1024 * 2048 * 4;
constexpr size_t OFF_V     = OFF_K + (size_t)1024 * 2048 * 4;
constexpr size_t OFF_G     = OFF_V + (size_t)1024 * 2048 * 4;   // scan over-read pad
constexpr size_t OFF_BETA  = OFF_G + (size_t)1024 * 16 * 4;
constexpr size_t OFF_GAB   = OFF_BETA + (size_t)1024 * 16 * 4;
constexpr size_t OFF_GATE  = OFF_GAB + (size_t)1024 * 128 * 2;
constexpr size_t OFF_O     = OFF_GATE + (size_t)1024 * 2048 * 4;
constexpr size_t OFF_OGB   = OFF_O + (size_t)1024 * 2048 * 4;
constexpr size_t OFF_OPROJ = OFF_OGB + (size_t)1024 * 2048 * 2;
constexpr size_t OFF_X1    = OFF_OPROJ + (size_t)1024 * 2048 * 4;
constexpr size_t OFF_H2B   = OFF_X1 + (size_t)1024 * 2048 * 4;
constexpr size_t OFF_MLP1   = A0;
constexpr size_t OFF_MID    = A0 + (size_t)1024 * 16384 * 4;
constexpr size_t OFF_MLPOUT = OFF_H2B + (size_t)1024 * 2048 * 2;
constexpr size_t OFF_QKB    = OFF_MLPOUT + (size_t)1024 * 2048 * 4;     // [1024][16] f32
constexpr size_t OFF_G4     = OFF_QKB + (size_t)1024 * 16 * 4;          // [1040][16] float4 (padded)
constexpr size_t OFF_MLPOUT2= OFF_G4 + (size_t)1040 * 16 * 16;
constexpr size_t WS_NEED    = OFF_MLPOUT2 + (size_t)1024 * 2048 * 4;

extern "C" void kernel_launch(void* const* d_in, const int* in_sizes, int n_in,
                              void* d_out, int out_size, void* d_ws, size_t ws_size,
                              hipStream_t stream) {
  (void)in_sizes; (void)n_in; (void)out_size;
  const float* x     = (const float*)d_in[0];
  const float* wq    = (const float*)d_in[1];
  const float* wk    = (const float*)d_in[2];
  const float* wv    = (const float*)d_in[3];
  const float* cq    = (const float*)d_in[4];
  const float* ck    = (const float*)d_in[5];
  const float* cv    = (const float*)d_in[6];
  const float* wfa   = (const float*)d_in[7];
  const float* wfb   = (const float*)d_in[8];
  const float* wb    = (const float*)d_in[9];
  const float* wga   = (const float*)d_in[10];
  const float* wgb   = (const float*)d_in[11];
  const float* a_log = (const float*)d_in[12];
  const float* dtb   = (const float*)d_in[13];
  const float* onw   = (const float*)d_in[14];
  const float* wo    = (const float*)d_in[15];
  const float* ln1   = (const float*)d_in[16];
  const float* ln2   = (const float*)d_in[17];
  const float* wgate = (const float*)d_in[18];
  const float* wup   = (const float*)d_in[19];
  const float* wdown = (const float*)d_in[20];
  float* out = (float*)d_out;
  char* ws = (char*)d_ws;
  if (ws_size < WS_NEED) return;

  unsigned short* wqkvT   = (unsigned short*)(ws + OFF_WQKVT);
  unsigned short* wsmallT = (unsigned short*)(ws + OFF_WSMALLT);
  unsigned short* wgbT    = (unsigned short*)(ws + OFF_WGBT);
  unsigned short* woT     = (unsigned short*)(ws + OFF_WOT);
  unsigned short* wmlp1T  = (unsigned short*)(ws + OFF_WMLP1T);
  unsigned short* wdownT  = (unsigned short*)(ws + OFF_WDOWNT);
  unsigned short* hb      = (unsigned short*)(ws + OFF_HB);
  float* projf  = (float*)(ws + OFF_PROJ);
  float* smallf = (float*)(ws + OFF_SMALL);
  float* qf     = (float*)(ws + OFF_Q);
  float* kf     = (float*)(ws + OFF_K);
  float* vf     = (float*)(ws + OFF_V);
  unsigned short* gab = (unsigned short*)(ws + OFF_GAB);
  float* gatef  = (float*)(ws + OFF_GATE);
  float* of     = (float*)(ws + OFF_O);
  unsigned short* ogb = (unsigned short*)(ws + OFF_OGB);
  float* oprojf = (float*)(ws + OFF_OPROJ);
  float* x1f    = (float*)(ws + OFF_X1);
  unsigned short* h2b = (unsigned short*)(ws + OFF_H2B);
  float* mlp1f  = (float*)(ws + OFF_MLP1);
  unsigned short* midb = (unsigned short*)(ws + OFF_MID);
  float* mlpoutf = (float*)(ws + OFF_MLPOUT);
  float* mlpout2f = (float*)(ws + OFF_MLPOUT2);
  float* qkbuf  = (float*)(ws + OFF_QKB);
  float4* g4    = (float4*)(ws + OFF_G4);

  trans_kernel<<<dim3(64, 64), 256, 0, stream>>>(wq, wqkvT, 2048, 2048);
  trans_kernel<<<dim3(64, 64), 256, 0, stream>>>(wk, wqkvT + (size_t)2048 * 2048, 2048, 2048);
  trans_kernel<<<dim3(64, 64), 256, 0, stream>>>(wv, wqkvT + (size_t)4096 * 2048, 2048, 2048);
  trans_kernel<<<dim3(4, 64), 256, 0, stream>>>(wfa, wsmallT, 2048, 128);
  trans_kernel<<<dim3(1, 64), 256, 0, stream>>>(wb, wsmallT + (size_t)128 * 2048, 2048, 16);
  trans_kernel<<<dim3(4, 64), 256, 0, stream>>>(wga, wsmallT + (size_t)144 * 2048, 2048, 128);
  trans_kernel<<<dim3(64, 4), 256, 0, stream>>>(wgb, wgbT, 128, 2048);
  trans_kernel<<<dim3(64, 64), 256, 0, stream>>>(wo, woT, 2048, 2048);
  trans_kernel<<<dim3(256, 64), 256, 0, stream>>>(wgate, wmlp1T, 2048, 8192);
  trans_kernel<<<dim3(256, 64), 256, 0, stream>>>(wup, wmlp1T + (size_t)8192 * 2048, 2048, 8192);
  trans_kernel<<<dim3(64, 256), 256, 0, stream>>>(wdown, wdownT, 8192, 2048);

  rmsnorm_bf16_kernel<<<1024, 256, 0, stream>>>(x, ln1, hb);
  gemm_bt_kernel<<<dim3(8, 48), 256, 0, stream>>>(hb, wqkvT, projf, 1024, 6144, 2048, 2048, 2048);
  gemm_bt_kernel<<<dim3(8, 3), 256, 0, stream>>>(hb, wsmallT, smallf, 1024, 272, 2048, 2048, 2048);
  conv_kernel<<<1024, 256, 0, stream>>>(projf, cq, ck, cv, qf, kf, vf, qkbuf);
  gates_kernel<<<1024, 64, 0, stream>>>(smallf, wfb, a_log, dtb, qkbuf, g4, gab);
  gemm_bt_kernel<<<dim3(8, 16), 256, 0, stream>>>(gab, wgbT, gatef, 1024, 2048, 128, 128, 128);
  scan_kernel<<<512, 64, 0, stream>>>(qf, kf, vf, g4, of);
  gate_o_kernel<<<1024, 256, 0, stream>>>(of, gatef, onw, ogb);
  gemm_bt_kernel<<<dim3(8, 16), 256, 0, stream>>>(ogb, woT, oprojf, 1024, 2048, 2048, 2048, 2048);
  add_rmsnorm_kernel<<<1024, 256, 0, stream>>>(x, oprojf, ln2, x1f, h2b);
  gemm_bt_kernel<<<dim3(8, 128), 256, 0, stream>>>(h2b, wmlp1T, mlp1f, 1024, 16384, 2048, 2048, 2048);
  swiglu_kernel<<<2048, 256, 0, stream>>>(mlp1f, midb);
  // split-K down-proj: two K=4096 halves on 2x128 blocks
  gemm_bt_kernel<<<dim3(8, 16), 256, 0, stream>>>(midb, wdownT, mlpoutf, 1024, 2048, 4096, 8192, 8192);
  gemm_bt_kernel<<<dim3(8, 16), 256, 0, stream>>>(midb + 4096, wdownT + 4096, mlpout2f, 1024, 2048, 4096, 8192, 8192);
  final_add3_kernel<<<2048, 256, 0, stream>>>(x1f, mlpoutf, mlpout2f, out);
}